// Round 17
// baseline (165.974 us; speedup 1.0000x reference)
//
#include <hip/hip_runtime.h>

#define BDIM 256
#define KC_STRIDE 28                  // per (case,co): K[0..24], bias at [25], 2 pad
#define CASE_STRIDE (32 * KC_STRIDE)  // 896 floats per border-case
#define SP 1032                       // S plane stride (16 rows x 64 + 8 pad)

typedef float floatx4 __attribute__((ext_vector_type(4)));

// case index along one axis: 0 (p==0), 1 (p==1), 2 (interior), 3 (p==62), 4 (p==63)
__device__ __forceinline__ int casef(int p) {
  return ((unsigned)(p - 2) < 60u) ? 2 : (p < 2 ? p : p - 59);
}

// ---------------- prep: collapsed 5x5 kernels, layout [case][co][28] ----------------
__global__ __launch_bounds__(BDIM) void prep_kernel(
    const float* __restrict__ W1, const float* __restrict__ b1,
    const float* __restrict__ W2, const float* __restrict__ b2,
    float* __restrict__ ws) {
  __shared__ float Mlds[9 * 9 * 32];
  __shared__ float BvL[9 * 32];
  const int tid = threadIdx.x;
  const int co = tid & 31;
  for (int tap = tid >> 5; tap < 9; tap += 8) {
    float acc[9] = {0.f, 0.f, 0.f, 0.f, 0.f, 0.f, 0.f, 0.f, 0.f};
    float accB = 0.f;
    for (int ci = 0; ci < 64; ++ci) {
      float w2 = W2[(tap * 64 + ci) * 32 + co];
      accB = fmaf(b1[ci], w2, accB);
#pragma unroll
      for (int e = 0; e < 9; ++e) acc[e] = fmaf(W1[e * 64 + ci], w2, acc[e]);
    }
#pragma unroll
    for (int e = 0; e < 9; ++e) Mlds[(tap * 9 + e) * 32 + co] = acc[e];
    BvL[tap * 32 + co] = accB;
  }
  __syncthreads();

  const int a = blockIdx.x / 5, c = blockIdx.x % 5;
  const int dmask[5] = {4, 6, 7, 3, 1};
  const int Da = dmask[a], Dc = dmask[c];
  for (int t = tid; t < CASE_STRIDE; t += BDIM) {
    int cc = t / KC_STRIDE, r = t % KC_STRIDE;
    float s = 0.f;
    if (r < 25) {
      int u = r / 5, v = r % 5;
      for (int di = 0; di < 3; ++di) {
        if (!((Da >> di) & 1)) continue;
        int ei = u - di;
        if ((unsigned)ei > 2u) continue;
        for (int dj = 0; dj < 3; ++dj) {
          if (!((Dc >> dj) & 1)) continue;
          int ej = v - dj;
          if ((unsigned)ej > 2u) continue;
          s += Mlds[((di * 3 + dj) * 9 + ei * 3 + ej) * 32 + cc];
        }
      }
    } else if (r == 25) {
      s = b2[cc];
      for (int di = 0; di < 3; ++di)
        if ((Da >> di) & 1)
          for (int dj = 0; dj < 3; ++dj)
            if ((Dc >> dj) & 1) s += BvL[(di * 3 + dj) * 32 + cc];
    }
    ws[blockIdx.x * CASE_STRIDE + t] = s;
  }
}

// ---- main: R9 pipelined structure (dump(t-1) at top of substage t, dbuf S,
// ---- one lgkm barrier per substage, vmcnt pacing) + NONTEMPORAL stores ----
__global__ __launch_bounds__(BDIM) void main_kernel(
    const float* __restrict__ x, const float* __restrict__ ws,
    float* __restrict__ out) {
  const int bb = blockIdx.x;
  const int b = bb >> 1;
  const int r0 = (bb & 1) << 5;  // 0 or 32
  const int tid = threadIdx.x;
  const int lane = tid & 63;
  const int wave = tid >> 6;

  __shared__ __align__(16) float xp[36 * 68];       // rows r0-2..r0+33, cols -2..65
  __shared__ __align__(16) float S[2][4][SP];       // dbuf x 4 planes of 16x64
  __shared__ __align__(16) float KiL[CASE_STRIDE];  // interior case (2,2)
  __shared__ unsigned long long Rm[32];
  __shared__ unsigned short aqi[2][224], aqb[2][64];
  __shared__ int nqi_sh[2], nqb_sh[2];

  if (tid < 2) { nqi_sh[tid] = 0; nqb_sh[tid] = 0; }
  float4* xp4 = reinterpret_cast<float4*>(xp);
  for (int i = tid; i < 612; i += BDIM) xp4[i] = make_float4(0.f, 0.f, 0.f, 0.f);
  for (int i = tid; i < CASE_STRIDE; i += BDIM) KiL[i] = ws[12 * CASE_STRIDE + i];
  __syncthreads();

  const float* xb = x + (size_t)b * 4096;
  for (int it = tid; it < 576; it += BDIM) {
    int i = it >> 4, c4 = (it & 15) << 2;
    int r = r0 - 2 + i;
    if ((unsigned)r < 64u) {
      float4 v = *reinterpret_cast<const float4*>(xb + r * 64 + c4);
      float2* d2 = reinterpret_cast<float2*>(&xp[i * 68 + 2 + c4]);
      d2[0] = make_float2(v.x, v.y);
      d2[1] = make_float2(v.z, v.w);
    }
  }
  __syncthreads();

  for (int k = wave; k < 32; k += 4) {
    int pred = (xp[(k + 2) * 68 + 2 + lane] != 0.0f);
    unsigned long long m = __ballot(pred);
    if (lane == 0) Rm[k] = m;
  }
  __syncthreads();

  for (int g = tid; g < 512; g += BDIM) {
    int k = g >> 4, q0 = (g & 15) << 2;
    unsigned bits = (unsigned)(Rm[k] >> q0) & 0xFu;
    if (!bits) continue;
    int h = k >> 4;
    int p = r0 + k;
    bool inter = ((unsigned)(p - 2) < 60u) && ((unsigned)(q0 - 4) <= 52u);
    if (inter) {
      aqi[h][atomicAdd(&nqi_sh[h], 1)] = (unsigned short)g;
    } else {
      aqb[h][atomicAdd(&nqb_sh[h], 1)] = (unsigned short)g;
    }
  }
  __syncthreads();

  const int ni0 = nqi_sh[0], ni1 = nqi_sh[1];
  const int nb0 = nqb_sh[0], nb1 = nqb_sh[1];
  float* outb = out + (size_t)b * (32 * 4096);

  // 16 substages: t -> (channel group cg = t>>1, row half h = t&1)
  for (int t = 0; t < 16; ++t) {
    const int cg = t >> 1, h = t & 1;
    // ---- dump(t-1): issue NT stores FIRST so they drain under this compute ----
    if (t > 0) {
      const int pt = t - 1;
      const int pcg = pt >> 1, ph = pt & 1;
      const int co = (pcg << 2) + wave;
      float* dst = outb + (((size_t)co) << 12) + ((r0 + (ph << 4)) << 6);
      const floatx4* Sp = reinterpret_cast<const floatx4*>(&S[pt & 1][wave][0]);
      asm volatile("s_waitcnt vmcnt(16)" ::: "memory");  // pace, never 0
#pragma unroll
      for (int i = 0; i < 4; ++i) {
        int f4 = (i << 6) + lane;
        int kk = f4 >> 4, q0 = (f4 & 15) << 2;
        unsigned bits = (unsigned)(Rm[(ph << 4) + kk] >> q0) & 0xFu;
        floatx4 v = Sp[f4];
        if (!(bits & 1u)) v.x = 0.f;
        if (!(bits & 2u)) v.y = 0.f;
        if (!(bits & 4u)) v.z = 0.f;
        if (!(bits & 8u)) v.w = 0.f;
        __builtin_nontemporal_store(v, reinterpret_cast<floatx4*>(dst + (f4 << 2)));
      }
    }
    // ---- compute(t): interior quads, item = (quad, co4) ----
    const int ni = h ? ni1 : ni0;
    const int nb = h ? nb1 : nb0;
    float(*Sc)[SP] = S[t & 1];
    for (int n = tid; n < ni * 4; n += BDIM) {
      int g = aqi[h][n >> 2];
      int co4 = n & 3;
      int co = (cg << 2) + co4;
      int k = g >> 4, q0 = (g & 15) << 2;
      const float* Kp = &KiL[co * KC_STRIDE];
      float bias = Kp[25];
      float z0 = bias, z1 = bias, z2 = bias, z3 = bias;
#pragma unroll
      for (int u = 0; u < 5; ++u) {
        const float* xr = &xp[(k + u) * 68 + q0];
        float4 xa = *reinterpret_cast<const float4*>(xr);
        float4 xc = *reinterpret_cast<const float4*>(xr + 4);
        float xv[8] = {xa.x, xa.y, xa.z, xa.w, xc.x, xc.y, xc.z, xc.w};
#pragma unroll
        for (int v = 0; v < 5; ++v) {
          float Kv = Kp[u * 5 + v];
          z0 = fmaf(xv[v], Kv, z0);
          z1 = fmaf(xv[v + 1], Kv, z1);
          z2 = fmaf(xv[v + 2], Kv, z2);
          z3 = fmaf(xv[v + 3], Kv, z3);
        }
      }
      *reinterpret_cast<float4*>(&Sc[co4][((k & 15) << 6) + q0]) =
          make_float4(z0, z1, z2, z3);
    }
    // ---- compute(t): border quads ----
    for (int n = tid; n < nb * 4; n += BDIM) {
      int g = aqb[h][n >> 2];
      int co4 = n & 3;
      int co = (cg << 2) + co4;
      int k = g >> 4, q0 = (g & 15) << 2;
      int p = r0 + k;
      int cp = casef(p);
      const float* K0 = ws + ((cp * 5 + casef(q0)) * 32 + co) * KC_STRIDE;
      const float* K1 = ws + ((cp * 5 + casef(q0 + 1)) * 32 + co) * KC_STRIDE;
      const float* K2 = ws + ((cp * 5 + casef(q0 + 2)) * 32 + co) * KC_STRIDE;
      const float* K3 = ws + ((cp * 5 + casef(q0 + 3)) * 32 + co) * KC_STRIDE;
      float z0 = K0[25], z1 = K1[25], z2 = K2[25], z3 = K3[25];
#pragma unroll
      for (int u = 0; u < 5; ++u) {
        const float* xr = &xp[(k + u) * 68 + q0];
        float4 xa = *reinterpret_cast<const float4*>(xr);
        float4 xc = *reinterpret_cast<const float4*>(xr + 4);
        float xv[8] = {xa.x, xa.y, xa.z, xa.w, xc.x, xc.y, xc.z, xc.w};
#pragma unroll
        for (int v = 0; v < 5; ++v) {
          int o = u * 5 + v;
          z0 = fmaf(xv[v], K0[o], z0);
          z1 = fmaf(xv[v + 1], K1[o], z1);
          z2 = fmaf(xv[v + 2], K2[o], z2);
          z3 = fmaf(xv[v + 3], K3[o], z3);
        }
      }
      *reinterpret_cast<float4*>(&Sc[co4][((k & 15) << 6) + q0]) =
          make_float4(z0, z1, z2, z3);
    }
    // ---- single lgkm-only barrier: S(t) visible, dump(t-1) reads done ----
    asm volatile("s_waitcnt lgkmcnt(0)" ::: "memory");
    __builtin_amdgcn_s_barrier();
  }
  // ---- epilogue: dump(15) ----
  {
    const int co = 28 + wave;
    float* dst = outb + (((size_t)co) << 12) + ((r0 + 16) << 6);
    const floatx4* Sp = reinterpret_cast<const floatx4*>(&S[1][wave][0]);
#pragma unroll
    for (int i = 0; i < 4; ++i) {
      int f4 = (i << 6) + lane;
      int kk = f4 >> 4, q0 = (f4 & 15) << 2;
      unsigned bits = (unsigned)(Rm[16 + kk] >> q0) & 0xFu;
      floatx4 v = Sp[f4];
      if (!(bits & 1u)) v.x = 0.f;
      if (!(bits & 2u)) v.y = 0.f;
      if (!(bits & 4u)) v.z = 0.f;
      if (!(bits & 8u)) v.w = 0.f;
      __builtin_nontemporal_store(v, reinterpret_cast<floatx4*>(dst + (f4 << 2)));
    }
  }
}

extern "C" void kernel_launch(void* const* d_in, const int* in_sizes, int n_in,
                              void* d_out, int out_size, void* d_ws, size_t ws_size,
                              hipStream_t stream) {
  const float* x  = (const float*)d_in[0];
  const float* W1 = (const float*)d_in[1];
  const float* b1 = (const float*)d_in[2];
  const float* W2 = (const float*)d_in[3];
  const float* b2 = (const float*)d_in[4];
  float* out = (float*)d_out;
  float* ws  = (float*)d_ws;
  int B = in_sizes[0] / 4096;  // 1024 images of 64x64x1

  hipLaunchKernelGGL(prep_kernel, dim3(25), dim3(BDIM), 0, stream, W1, b1, W2, b2, ws);
  hipLaunchKernelGGL(main_kernel, dim3(2 * B), dim3(BDIM), 0, stream, x, ws, out);
}

// Round 18
// 135.969 us; speedup vs baseline: 1.2207x; 1.2207x over previous
//
#include <hip/hip_runtime.h>

#define BDIM 256
#define KC_STRIDE 28                  // per (case,co): K[0..24], bias at [25], 2 pad
#define CASE_STRIDE (32 * KC_STRIDE)  // 896 floats per border-case
#define SP 1032                       // S plane stride (16 rows x 64 + 8 pad)

typedef float floatx4 __attribute__((ext_vector_type(4)));

// case index along one axis: 0 (p==0), 1 (p==1), 2 (interior), 3 (p==62), 4 (p==63)
__device__ __forceinline__ int casef(int p) {
  return ((unsigned)(p - 2) < 60u) ? 2 : (p < 2 ? p : p - 59);
}

// ---------------- prep: collapsed 5x5 kernels, layout [case][co][28] ----------------
__global__ __launch_bounds__(BDIM) void prep_kernel(
    const float* __restrict__ W1, const float* __restrict__ b1,
    const float* __restrict__ W2, const float* __restrict__ b2,
    float* __restrict__ ws) {
  __shared__ float Mlds[9 * 9 * 32];
  __shared__ float BvL[9 * 32];
  const int tid = threadIdx.x;
  const int co = tid & 31;
  for (int tap = tid >> 5; tap < 9; tap += 8) {
    float acc[9] = {0.f, 0.f, 0.f, 0.f, 0.f, 0.f, 0.f, 0.f, 0.f};
    float accB = 0.f;
    for (int ci = 0; ci < 64; ++ci) {
      float w2 = W2[(tap * 64 + ci) * 32 + co];
      accB = fmaf(b1[ci], w2, accB);
#pragma unroll
      for (int e = 0; e < 9; ++e) acc[e] = fmaf(W1[e * 64 + ci], w2, acc[e]);
    }
#pragma unroll
    for (int e = 0; e < 9; ++e) Mlds[(tap * 9 + e) * 32 + co] = acc[e];
    BvL[tap * 32 + co] = accB;
  }
  __syncthreads();

  const int a = blockIdx.x / 5, c = blockIdx.x % 5;
  const int dmask[5] = {4, 6, 7, 3, 1};
  const int Da = dmask[a], Dc = dmask[c];
  for (int t = tid; t < CASE_STRIDE; t += BDIM) {
    int cc = t / KC_STRIDE, r = t % KC_STRIDE;
    float s = 0.f;
    if (r < 25) {
      int u = r / 5, v = r % 5;
      for (int di = 0; di < 3; ++di) {
        if (!((Da >> di) & 1)) continue;
        int ei = u - di;
        if ((unsigned)ei > 2u) continue;
        for (int dj = 0; dj < 3; ++dj) {
          if (!((Dc >> dj) & 1)) continue;
          int ej = v - dj;
          if ((unsigned)ej > 2u) continue;
          s += Mlds[((di * 3 + dj) * 9 + ei * 3 + ej) * 32 + cc];
        }
      }
    } else if (r == 25) {
      s = b2[cc];
      for (int di = 0; di < 3; ++di)
        if ((Da >> di) & 1)
          for (int dj = 0; dj < 3; ++dj)
            if ((Dc >> dj) & 1) s += BvL[(di * 3 + dj) * 32 + cc];
    }
    ws[blockIdx.x * CASE_STRIDE + t] = s;
  }
}

// ---- main: champion + co-pairing (2 channels per window read); 8 substages,
// ---- 16-row planes, same barrier/dump counts as champion; NT stores ----
__global__ __launch_bounds__(BDIM) void main_kernel(
    const float* __restrict__ x, const float* __restrict__ ws,
    float* __restrict__ out) {
  const int bb = blockIdx.x;
  const int b = bb >> 1;
  const int r0 = (bb & 1) << 5;  // 0 or 32
  const int tid = threadIdx.x;
  const int lane = tid & 63;
  const int wave = tid >> 6;

  __shared__ __align__(16) float xp[36 * 68];       // rows r0-2..r0+33, cols -2..65
  __shared__ __align__(16) float S[8][SP];          // 8 planes of 16x64 (+pad)
  __shared__ __align__(16) float KiL[CASE_STRIDE];  // interior case (2,2)
  __shared__ unsigned long long Rm[32];
  __shared__ unsigned short aqi[2][224], aqb[2][64];
  __shared__ int nqi_sh[2], nqb_sh[2];

  if (tid < 2) { nqi_sh[tid] = 0; nqb_sh[tid] = 0; }
  float4* xp4 = reinterpret_cast<float4*>(xp);
  for (int i = tid; i < 612; i += BDIM) xp4[i] = make_float4(0.f, 0.f, 0.f, 0.f);
  for (int i = tid; i < CASE_STRIDE; i += BDIM) KiL[i] = ws[12 * CASE_STRIDE + i];
  __syncthreads();

  const float* xb = x + (size_t)b * 4096;
  for (int it = tid; it < 576; it += BDIM) {
    int i = it >> 4, c4 = (it & 15) << 2;
    int r = r0 - 2 + i;
    if ((unsigned)r < 64u) {
      float4 v = *reinterpret_cast<const float4*>(xb + r * 64 + c4);
      float2* d2 = reinterpret_cast<float2*>(&xp[i * 68 + 2 + c4]);
      d2[0] = make_float2(v.x, v.y);
      d2[1] = make_float2(v.z, v.w);
    }
  }
  __syncthreads();

  for (int k = wave; k < 32; k += 4) {
    int pred = (xp[(k + 2) * 68 + 2 + lane] != 0.0f);
    unsigned long long m = __ballot(pred);
    if (lane == 0) Rm[k] = m;
  }
  __syncthreads();

  for (int g = tid; g < 512; g += BDIM) {
    int k = g >> 4, q0 = (g & 15) << 2;
    unsigned bits = (unsigned)(Rm[k] >> q0) & 0xFu;
    if (!bits) continue;
    int h = k >> 4;
    int p = r0 + k;
    bool inter = ((unsigned)(p - 2) < 60u) && ((unsigned)(q0 - 4) <= 52u);
    if (inter) {
      aqi[h][atomicAdd(&nqi_sh[h], 1)] = (unsigned short)g;
    } else {
      aqb[h][atomicAdd(&nqb_sh[h], 1)] = (unsigned short)g;
    }
  }
  __syncthreads();

  const int ni0 = nqi_sh[0], ni1 = nqi_sh[1];
  const int nb0 = nqb_sh[0], nb1 = nqb_sh[1];
  float* outb = out + (size_t)b * (32 * 4096);

  // 8 substages: t -> (channel octet cg = t>>1, row half h = t&1)
  for (int t = 0; t < 8; ++t) {
    const int cg = t >> 1, h = t & 1;
    const int ni = h ? ni1 : ni0;
    const int nb = h ? nb1 : nb0;
    // ---- interior quads: item = (quad, co4); thread computes co and co+4 ----
    for (int n = tid; n < ni * 4; n += BDIM) {
      int g = aqi[h][n >> 2];
      int co4 = n & 3;  // == tid&3, lane-static
      int co_lo = (cg << 3) + co4;
      int k = g >> 4, q0 = (g & 15) << 2;
      const float* Ka = &KiL[co_lo * KC_STRIDE];
      const float* Kb = &KiL[(co_lo + 4) * KC_STRIDE];
      float ba = Ka[25], bbv = Kb[25];
      float a0 = ba, a1 = ba, a2 = ba, a3 = ba;
      float b0 = bbv, b1 = bbv, b2 = bbv, b3 = bbv;
#pragma unroll
      for (int u = 0; u < 5; ++u) {
        const float* xr = &xp[(k + u) * 68 + q0];
        float4 xa = *reinterpret_cast<const float4*>(xr);
        float4 xc = *reinterpret_cast<const float4*>(xr + 4);
        float xv[8] = {xa.x, xa.y, xa.z, xa.w, xc.x, xc.y, xc.z, xc.w};
#pragma unroll
        for (int v = 0; v < 5; ++v) {
          float ka = Ka[u * 5 + v], kb = Kb[u * 5 + v];
          a0 = fmaf(xv[v], ka, a0);
          a1 = fmaf(xv[v + 1], ka, a1);
          a2 = fmaf(xv[v + 2], ka, a2);
          a3 = fmaf(xv[v + 3], ka, a3);
          b0 = fmaf(xv[v], kb, b0);
          b1 = fmaf(xv[v + 1], kb, b1);
          b2 = fmaf(xv[v + 2], kb, b2);
          b3 = fmaf(xv[v + 3], kb, b3);
        }
      }
      int so = ((k & 15) << 6) + q0;
      *reinterpret_cast<float4*>(&S[co4][so]) = make_float4(a0, a1, a2, a3);
      *reinterpret_cast<float4*>(&S[co4 + 4][so]) = make_float4(b0, b1, b2, b3);
    }
    // ---- border quads: item = (quad, cs of 8); 1 channel each ----
    for (int n = tid; n < nb * 8; n += BDIM) {
      int g = aqb[h][n >> 3];
      int cs = n & 7;  // == tid&7, lane-static
      int co = (cg << 3) + cs;
      int k = g >> 4, q0 = (g & 15) << 2;
      int p = r0 + k;
      int cp = casef(p);
      const float* K0 = ws + ((cp * 5 + casef(q0)) * 32 + co) * KC_STRIDE;
      const float* K1 = ws + ((cp * 5 + casef(q0 + 1)) * 32 + co) * KC_STRIDE;
      const float* K2 = ws + ((cp * 5 + casef(q0 + 2)) * 32 + co) * KC_STRIDE;
      const float* K3 = ws + ((cp * 5 + casef(q0 + 3)) * 32 + co) * KC_STRIDE;
      float z0 = K0[25], z1 = K1[25], z2 = K2[25], z3 = K3[25];
#pragma unroll
      for (int u = 0; u < 5; ++u) {
        const float* xr = &xp[(k + u) * 68 + q0];
        float4 xa = *reinterpret_cast<const float4*>(xr);
        float4 xc = *reinterpret_cast<const float4*>(xr + 4);
        float xv[8] = {xa.x, xa.y, xa.z, xa.w, xc.x, xc.y, xc.z, xc.w};
#pragma unroll
        for (int v = 0; v < 5; ++v) {
          int o = u * 5 + v;
          z0 = fmaf(xv[v], K0[o], z0);
          z1 = fmaf(xv[v + 1], K1[o], z1);
          z2 = fmaf(xv[v + 2], K2[o], z2);
          z3 = fmaf(xv[v + 3], K3[o], z3);
        }
      }
      *reinterpret_cast<float4*>(&S[cs][((k & 15) << 6) + q0]) =
          make_float4(z0, z1, z2, z3);
    }
    // ---- drain-free barrier: LDS visibility only; stores stay in flight ----
    asm volatile("s_waitcnt lgkmcnt(0)" ::: "memory");
    __builtin_amdgcn_s_barrier();
    // ---- dump: wave w -> planes w and w+4 (16 rows each), NT stores ----
    {
      int co_a = (cg << 3) + wave;
      int co_b = co_a + 4;
      float* dstA = outb + (((size_t)co_a) << 12) + ((r0 + (h << 4)) << 6);
      float* dstB = outb + (((size_t)co_b) << 12) + ((r0 + (h << 4)) << 6);
      const floatx4* SpA = reinterpret_cast<const floatx4*>(&S[wave][0]);
      const floatx4* SpB = reinterpret_cast<const floatx4*>(&S[wave + 4][0]);
#pragma unroll
      for (int i = 0; i < 4; ++i) {
        int f4 = (i << 6) + lane;
        int kk = f4 >> 4, q0 = (f4 & 15) << 2;
        unsigned bits = (unsigned)(Rm[(h << 4) + kk] >> q0) & 0xFu;
        floatx4 va = SpA[f4];
        floatx4 vb = SpB[f4];
        if (!(bits & 1u)) { va.x = 0.f; vb.x = 0.f; }
        if (!(bits & 2u)) { va.y = 0.f; vb.y = 0.f; }
        if (!(bits & 4u)) { va.z = 0.f; vb.z = 0.f; }
        if (!(bits & 8u)) { va.w = 0.f; vb.w = 0.f; }
        __builtin_nontemporal_store(va, reinterpret_cast<floatx4*>(dstA + (f4 << 2)));
        __builtin_nontemporal_store(vb, reinterpret_cast<floatx4*>(dstB + (f4 << 2)));
      }
    }
    // ---- WAR barrier before next substage overwrites S ----
    asm volatile("s_waitcnt lgkmcnt(0)" ::: "memory");
    __builtin_amdgcn_s_barrier();
  }
}

extern "C" void kernel_launch(void* const* d_in, const int* in_sizes, int n_in,
                              void* d_out, int out_size, void* d_ws, size_t ws_size,
                              hipStream_t stream) {
  const float* x  = (const float*)d_in[0];
  const float* W1 = (const float*)d_in[1];
  const float* b1 = (const float*)d_in[2];
  const float* W2 = (const float*)d_in[3];
  const float* b2 = (const float*)d_in[4];
  float* out = (float*)d_out;
  float* ws  = (float*)d_ws;
  int B = in_sizes[0] / 4096;  // 1024 images of 64x64x1

  hipLaunchKernelGGL(prep_kernel, dim3(25), dim3(BDIM), 0, stream, W1, b1, W2, b2, ws);
  hipLaunchKernelGGL(main_kernel, dim3(2 * B), dim3(BDIM), 0, stream, x, ws, out);
}

// Round 19
// 135.119 us; speedup vs baseline: 1.2284x; 1.0063x over previous
//
#include <hip/hip_runtime.h>

#define BDIM 256
#define KC_STRIDE 28                  // per (case,co): K[0..24], bias at [25], 2 pad
#define CASE_STRIDE (32 * KC_STRIDE)  // 896 floats per border-case
#define SP 1028                       // S plane stride (16 rows x 64 + 4 pad)

typedef float floatx4 __attribute__((ext_vector_type(4)));

// case index along one axis: 0 (p==0), 1 (p==1), 2 (interior), 3 (p==62), 4 (p==63)
__device__ __forceinline__ int casef(int p) {
  return ((unsigned)(p - 2) < 60u) ? 2 : (p < 2 ? p : p - 59);
}

// ---------------- prep: collapsed 5x5 kernels, layout [case][co][28] ----------------
__global__ __launch_bounds__(BDIM) void prep_kernel(
    const float* __restrict__ W1, const float* __restrict__ b1,
    const float* __restrict__ W2, const float* __restrict__ b2,
    float* __restrict__ ws) {
  __shared__ float Mlds[9 * 9 * 32];
  __shared__ float BvL[9 * 32];
  const int tid = threadIdx.x;
  const int co = tid & 31;
  for (int tap = tid >> 5; tap < 9; tap += 8) {
    float acc[9] = {0.f, 0.f, 0.f, 0.f, 0.f, 0.f, 0.f, 0.f, 0.f};
    float accB = 0.f;
    for (int ci = 0; ci < 64; ++ci) {
      float w2 = W2[(tap * 64 + ci) * 32 + co];
      accB = fmaf(b1[ci], w2, accB);
#pragma unroll
      for (int e = 0; e < 9; ++e) acc[e] = fmaf(W1[e * 64 + ci], w2, acc[e]);
    }
#pragma unroll
    for (int e = 0; e < 9; ++e) Mlds[(tap * 9 + e) * 32 + co] = acc[e];
    BvL[tap * 32 + co] = accB;
  }
  __syncthreads();

  const int a = blockIdx.x / 5, c = blockIdx.x % 5;
  const int dmask[5] = {4, 6, 7, 3, 1};
  const int Da = dmask[a], Dc = dmask[c];
  for (int t = tid; t < CASE_STRIDE; t += BDIM) {
    int cc = t / KC_STRIDE, r = t % KC_STRIDE;
    float s = 0.f;
    if (r < 25) {
      int u = r / 5, v = r % 5;
      for (int di = 0; di < 3; ++di) {
        if (!((Da >> di) & 1)) continue;
        int ei = u - di;
        if ((unsigned)ei > 2u) continue;
        for (int dj = 0; dj < 3; ++dj) {
          if (!((Dc >> dj) & 1)) continue;
          int ej = v - dj;
          if ((unsigned)ej > 2u) continue;
          s += Mlds[((di * 3 + dj) * 9 + ei * 3 + ej) * 32 + cc];
        }
      }
    } else if (r == 25) {
      s = b2[cc];
      for (int di = 0; di < 3; ++di)
        if ((Da >> di) & 1)
          for (int dj = 0; dj < 3; ++dj)
            if ((Dc >> dj) & 1) s += BvL[(di * 3 + dj) * 32 + cc];
    }
    ws[blockIdx.x * CASE_STRIDE + t] = s;
  }
}

// ---- main: wave-owned channel octets, 4-lane-shared windows, ZERO in-loop
// ---- barriers, wave-private S planes, NT stores ----
__global__ __launch_bounds__(BDIM) void main_kernel(
    const float* __restrict__ x, const float* __restrict__ ws,
    float* __restrict__ out) {
  const int bb = blockIdx.x;
  const int b = bb >> 1;
  const int r0 = (bb & 1) << 5;  // 0 or 32
  const int tid = threadIdx.x;
  const int lane = tid & 63;
  const int wave = tid >> 6;

  __shared__ __align__(16) float xp[36 * 68];   // rows r0-2..r0+33, cols -2..65
  __shared__ __align__(16) float S[4][4][SP];   // [wave][plane][16x64 (+pad)]
  __shared__ unsigned long long Rm[32];
  __shared__ unsigned short aqi[2][224], aqb[2][64];
  __shared__ int nqi_sh[2], nqb_sh[2];

  if (tid < 2) { nqi_sh[tid] = 0; nqb_sh[tid] = 0; }
  float4* xp4 = reinterpret_cast<float4*>(xp);
  for (int i = tid; i < 612; i += BDIM) xp4[i] = make_float4(0.f, 0.f, 0.f, 0.f);
  __syncthreads();

  const float* xb = x + (size_t)b * 4096;
  for (int it = tid; it < 576; it += BDIM) {
    int i = it >> 4, c4 = (it & 15) << 2;
    int r = r0 - 2 + i;
    if ((unsigned)r < 64u) {
      float4 v = *reinterpret_cast<const float4*>(xb + r * 64 + c4);
      float2* d2 = reinterpret_cast<float2*>(&xp[i * 68 + 2 + c4]);
      d2[0] = make_float2(v.x, v.y);
      d2[1] = make_float2(v.z, v.w);
    }
  }
  __syncthreads();

  for (int k = wave; k < 32; k += 4) {
    int pred = (xp[(k + 2) * 68 + 2 + lane] != 0.0f);
    unsigned long long m = __ballot(pred);
    if (lane == 0) Rm[k] = m;
  }
  __syncthreads();

  for (int g = tid; g < 512; g += BDIM) {
    int k = g >> 4, q0 = (g & 15) << 2;
    unsigned bits = (unsigned)(Rm[k] >> q0) & 0xFu;
    if (!bits) continue;
    int h = k >> 4;
    int p = r0 + k;
    bool inter = ((unsigned)(p - 2) < 60u) && ((unsigned)(q0 - 4) <= 52u);
    if (inter) {
      aqi[h][atomicAdd(&nqi_sh[h], 1)] = (unsigned short)g;
    } else {
      aqb[h][atomicAdd(&nqb_sh[h], 1)] = (unsigned short)g;
    }
  }
  __syncthreads();  // last block-wide barrier; waves free-run from here

  float* outb = out + (size_t)b * (32 * 4096);
  const float* wsKi = ws + 12 * CASE_STRIDE;  // interior case (2,2)
  const int co4 = lane & 3;

  for (int cg = 0; cg < 2; ++cg) {
    const int co = (wave << 3) + (cg << 2) + co4;  // this lane's channel
    // hoist interior kernel into VGPRs (L2-hot, 26 dwords, once per cg)
    float K[26];
    {
      const float* Kp = wsKi + co * KC_STRIDE;
#pragma unroll
      for (int j = 0; j < 26; ++j) K[j] = Kp[j];
    }
    for (int h = 0; h < 2; ++h) {
      const int ni = nqi_sh[h], nb = nqb_sh[h];
      // ---- interior quads: item = (quad, co4); 4 lanes share a window ----
      for (int n = lane; n < ni * 4; n += 64) {
        int g = aqi[h][n >> 2];
        int k = g >> 4, q0 = (g & 15) << 2;
        float bias = K[25];
        float z0 = bias, z1 = bias, z2 = bias, z3 = bias;
#pragma unroll
        for (int u = 0; u < 5; ++u) {
          const float* xr = &xp[(k + u) * 68 + q0];
          float4 xa = *reinterpret_cast<const float4*>(xr);
          float4 xc = *reinterpret_cast<const float4*>(xr + 4);
          float xv[8] = {xa.x, xa.y, xa.z, xa.w, xc.x, xc.y, xc.z, xc.w};
#pragma unroll
          for (int v = 0; v < 5; ++v) {
            float Kv = K[u * 5 + v];
            z0 = fmaf(xv[v], Kv, z0);
            z1 = fmaf(xv[v + 1], Kv, z1);
            z2 = fmaf(xv[v + 2], Kv, z2);
            z3 = fmaf(xv[v + 3], Kv, z3);
          }
        }
        *reinterpret_cast<float4*>(&S[wave][co4][((k & 15) << 6) + q0]) =
            make_float4(z0, z1, z2, z3);
      }
      // ---- border quads: per-pixel case, K from global (L2-hot) ----
      for (int n = lane; n < nb * 4; n += 64) {
        int g = aqb[h][n >> 2];
        int k = g >> 4, q0 = (g & 15) << 2;
        int p = r0 + k;
        int cp = casef(p);
        const float* K0 = ws + ((cp * 5 + casef(q0)) * 32 + co) * KC_STRIDE;
        const float* K1 = ws + ((cp * 5 + casef(q0 + 1)) * 32 + co) * KC_STRIDE;
        const float* K2 = ws + ((cp * 5 + casef(q0 + 2)) * 32 + co) * KC_STRIDE;
        const float* K3 = ws + ((cp * 5 + casef(q0 + 3)) * 32 + co) * KC_STRIDE;
        float z0 = K0[25], z1 = K1[25], z2 = K2[25], z3 = K3[25];
#pragma unroll
        for (int u = 0; u < 5; ++u) {
          const float* xr = &xp[(k + u) * 68 + q0];
          float4 xa = *reinterpret_cast<const float4*>(xr);
          float4 xc = *reinterpret_cast<const float4*>(xr + 4);
          float xv[8] = {xa.x, xa.y, xa.z, xa.w, xc.x, xc.y, xc.z, xc.w};
#pragma unroll
          for (int v = 0; v < 5; ++v) {
            int o = u * 5 + v;
            z0 = fmaf(xv[v], K0[o], z0);
            z1 = fmaf(xv[v + 1], K1[o], z1);
            z2 = fmaf(xv[v + 2], K2[o], z2);
            z3 = fmaf(xv[v + 3], K3[o], z3);
          }
        }
        *reinterpret_cast<float4*>(&S[wave][co4][((k & 15) << 6) + q0]) =
            make_float4(z0, z1, z2, z3);
      }
      // ---- intra-wave ordering only: S writes visible to own dump reads ----
      asm volatile("s_waitcnt lgkmcnt(0)" ::: "memory");
      // ---- dump this wave's 4 planes (16 rows each), NT stores ----
#pragma unroll
      for (int pl = 0; pl < 4; ++pl) {
        int c2 = (wave << 3) + (cg << 2) + pl;
        float* dst = outb + (((size_t)c2) << 12) + ((r0 + (h << 4)) << 6);
        const floatx4* Sp = reinterpret_cast<const floatx4*>(&S[wave][pl][0]);
#pragma unroll
        for (int i = 0; i < 4; ++i) {
          int f4 = (i << 6) + lane;
          int kk = f4 >> 4, q0 = (f4 & 15) << 2;
          unsigned bits = (unsigned)(Rm[(h << 4) + kk] >> q0) & 0xFu;
          floatx4 v = Sp[f4];
          if (!(bits & 1u)) v.x = 0.f;
          if (!(bits & 2u)) v.y = 0.f;
          if (!(bits & 4u)) v.z = 0.f;
          if (!(bits & 8u)) v.w = 0.f;
          __builtin_nontemporal_store(v, reinterpret_cast<floatx4*>(dst + (f4 << 2)));
        }
      }
      // same-wave DS ops retire in order: next pass's S writes can't pass the
      // dump's S reads; no wait needed beyond the implicit data deps
    }
  }
}

extern "C" void kernel_launch(void* const* d_in, const int* in_sizes, int n_in,
                              void* d_out, int out_size, void* d_ws, size_t ws_size,
                              hipStream_t stream) {
  const float* x  = (const float*)d_in[0];
  const float* W1 = (const float*)d_in[1];
  const float* b1 = (const float*)d_in[2];
  const float* W2 = (const float*)d_in[3];
  const float* b2 = (const float*)d_in[4];
  float* out = (float*)d_out;
  float* ws  = (float*)d_ws;
  int B = in_sizes[0] / 4096;  // 1024 images of 64x64x1

  hipLaunchKernelGGL(prep_kernel, dim3(25), dim3(BDIM), 0, stream, W1, b1, W2, b2, ws);
  hipLaunchKernelGGL(main_kernel, dim3(2 * B), dim3(BDIM), 0, stream, x, ws, out);
}